// Round 14
// baseline (179.524 us; speedup 1.0000x reference)
//
#include <hip/hip_runtime.h>
#include <hip/hip_bf16.h>
#include <stdint.h>

#define B_ 2
#define N_ 9
#define CB_ 80
#define H_ 120
#define W_ 160
#define D_ 64
#define P_ 80000
#define HW_ (H_*W_)        // 19200
#define NPIX_ (B_*N_*HW_)  // 345600
#define NEG_ (-10000.0f)

using short8 = __attribute__((ext_vector_type(8))) short;
using f32x4  = __attribute__((ext_vector_type(4))) float;

static __device__ __forceinline__ float bflo(uint32_t u) {
    return __uint_as_float(u << 16);
}
static __device__ __forceinline__ float bfhi(uint32_t u) {
    return __uint_as_float(u & 0xffff0000u);
}
// RNE float->bf16 bits
static __device__ __forceinline__ uint32_t f2bf_bits(float f) {
    uint32_t u = __float_as_uint(f);
    return (u + 0x7fffu + ((u >> 16) & 1u)) >> 16;
}

// 64-lane sum entirely on the VALU pipe (DPP), no DS ops.
static __device__ __forceinline__ float wave_sum64_dpp(float x) {
    float f = x;
    f += __int_as_float(__builtin_amdgcn_update_dpp(0, __float_as_int(f), 0x111, 0xF, 0xF, true));
    f += __int_as_float(__builtin_amdgcn_update_dpp(0, __float_as_int(f), 0x112, 0xF, 0xF, true));
    f += __int_as_float(__builtin_amdgcn_update_dpp(0, __float_as_int(f), 0x114, 0xF, 0xF, true));
    f += __int_as_float(__builtin_amdgcn_update_dpp(0, __float_as_int(f), 0x118, 0xF, 0xF, true));
    f += __int_as_float(__builtin_amdgcn_update_dpp(0, __float_as_int(f), 0x142, 0xA, 0xF, true));
    f += __int_as_float(__builtin_amdgcn_update_dpp(0, __float_as_int(f), 0x143, 0xC, 0xF, true));
    return __int_as_float(__builtin_amdgcn_readlane(__float_as_int(f), 63));  // uniform
}
static __device__ __forceinline__ float readlane_f(float v, int l) {
    return __int_as_float(__builtin_amdgcn_readlane(__float_as_int(v), l));
}

// ws layout (bytes)
#define OFF_KM    0
#define OFF_Q1S   ((size_t)NPIX_ * 64 * 4)                 // 88,473,600
#define OFF_SELCV (OFF_Q1S + (size_t)P_ * 64 * 4)          // +20,480,000
#define OFF_SELIX (OFF_SELCV + (size_t)P_ * 16)            // +1,280,000
#define OFF_NSEL  (OFF_SELIX + (size_t)P_ * 4)             // +320,000

// ---------------------------------------------------------------------------
// Kernel 1: key_maps via MFMA, v3: two sequential set-passes so only ONE
// 32-VGPR accumulator bank is live -> fits 64 VGPR (8-wave class; LDS caps
// residency at 6 blocks/CU = 75% occupancy). B-frags reloaded per k-chunk
// from L2-hot weights; each pass stores its bf16 half (global_store_short,
// halves merge in L2).
// ---------------------------------------------------------------------------
__global__ __launch_bounds__(256, 8) void keymap_mfma_kernel(
    const float* __restrict__ img,
    const float* __restrict__ Wk1, const float* __restrict__ bk1,
    const float* __restrict__ Wk2, const float* __restrict__ bk2,
    uint32_t* __restrict__ km)
{
    // row stride 104 bf16 = 208 B = 13*16 B: b128-aligned; rows 0..7 cover all
    // 32 banks exactly once -> b128 read/write at the bank floor
    __shared__ short a_lds[128][104];   // a[px][k] (bf16 bits), 26.6 KB
    const int tid  = threadIdx.x;
    const int lane = tid & 63;
    const int wv   = tid >> 6;
    const int lr   = lane & 15;
    const int lg   = lane >> 4;
    const int dw   = (wv >> 1) * 32;     // wave's d half
    const int pxw  = (wv & 1) * 64;      // wave's pixel half

    // ---- A tile -> LDS: thread owns (px, k-octet); b128 writes ----
    const int pix0 = blockIdx.x * 128;
    const int bn   = pix0 / HW_;
    const int hw0  = pix0 - bn * HW_;
    const float* ibase = img + (size_t)bn * CB_ * HW_ + hw0;
    {
        const int px = tid & 127;
        const int kh = (tid >> 7) * 48;          // 0 or 48
        #pragma unroll
        for (int oct = 0; oct < 6; oct++) {
            const int k = kh + oct * 8;
            short8 v = {0,0,0,0,0,0,0,0};
            if (k < 80) {
                #pragma unroll
                for (int j = 0; j < 8; j++)
                    v[j] = (short)f2bf_bits(ibase[(k + j) * HW_ + px]);
            }
            *reinterpret_cast<short8*>(&a_lds[px][k]) = v;
        }
    }
    __syncthreads();

    uint16_t* km16 = reinterpret_cast<uint16_t*>(km);

    #pragma unroll 1                      // keep set-passes SEQUENTIAL (VGPR)
    for (int s = 0; s < 2; s++) {
        const float* Wk = s ? Wk2 : Wk1;
        const float* bk = s ? bk2 : bk1;

        f32x4 acc[4][2];
        #pragma unroll
        for (int mi = 0; mi < 4; mi++)
            #pragma unroll
            for (int ni = 0; ni < 2; ni++)
                acc[mi][ni] = (f32x4){0.f, 0.f, 0.f, 0.f};

        #pragma unroll
        for (int kc = 0; kc < 3; kc++) {
            const int k0 = kc * 32;
            // B frags for this k-chunk (L2-hot)
            short8 bv[2];
            #pragma unroll
            for (int ni = 0; ni < 2; ni++) {
                const int d = dw + ni * 16 + lr;
                const int k = k0 + lg * 8;
                short8 v = {0,0,0,0,0,0,0,0};
                if (k < 80) {
                    const float4* p = reinterpret_cast<const float4*>(Wk + d * 80 + k);
                    float4 a0 = p[0], a1 = p[1];
                    v[0] = (short)f2bf_bits(a0.x); v[1] = (short)f2bf_bits(a0.y);
                    v[2] = (short)f2bf_bits(a0.z); v[3] = (short)f2bf_bits(a0.w);
                    v[4] = (short)f2bf_bits(a1.x); v[5] = (short)f2bf_bits(a1.y);
                    v[6] = (short)f2bf_bits(a1.z); v[7] = (short)f2bf_bits(a1.w);
                }
                bv[ni] = v;
            }
            #pragma unroll
            for (int mi = 0; mi < 4; mi++) {
                short8 av = *reinterpret_cast<const short8*>(
                    &a_lds[pxw + mi * 16 + lr][k0 + lg * 8]);
                acc[mi][0] = __builtin_amdgcn_mfma_f32_16x16x32_bf16(av, bv[0], acc[mi][0], 0, 0, 0);
                acc[mi][1] = __builtin_amdgcn_mfma_f32_16x16x32_bf16(av, bv[1], acc[mi][1], 0, 0, 0);
            }
        }

        // epilogue: add bias, store this set's bf16 half
        #pragma unroll
        for (int ni = 0; ni < 2; ni++) {
            const int d = dw + ni * 16 + lr;
            const float b = bk[d];
            #pragma unroll
            for (int mi = 0; mi < 4; mi++) {
                #pragma unroll
                for (int r = 0; r < 4; r++) {
                    int pix = pix0 + pxw + mi * 16 + lg * 4 + r;
                    km16[((size_t)pix * 64 + d) * 2 + s] =
                        (uint16_t)f2bf_bits(acc[mi][ni][r] + b);
                }
            }
        }
    }
}

// ---------------------------------------------------------------------------
// Kernel 1b: q1 prepass + out-init + SEL COMPACTION.  (unchanged)
// ---------------------------------------------------------------------------
__global__ __launch_bounds__(256) void qinit_kernel(
    const float* __restrict__ vfeat,
    const float* __restrict__ Wq1, const float* __restrict__ bq1,
    const int*   __restrict__ cmask,
    const int4*  __restrict__ coords4,
    float* __restrict__ q1s, float* __restrict__ out,
    int* __restrict__ sel_idx, int4* __restrict__ selcv, int* __restrict__ nsel)
{
    __shared__ float wt_lds[64][68];   // wt[c][d] = Wq1[d][c], padded
    __shared__ float vf_lds[64][68];
    __shared__ float bq_lds[64];
    const int tid = threadIdx.x;
    const int pt0 = blockIdx.x * 64;

    if (tid < 64) {
        int p2 = pt0 + tid;
        bool s = cmask[p2] > 1;
        unsigned long long m = __ballot(s);
        int base = 0;
        if (tid == 0 && m) base = atomicAdd(nsel, __popcll(m));
        base = __shfl(base, 0);
        if (s) {
            int off = __popcll(m & ((1ull << tid) - 1ull));
            sel_idx[base + off] = p2;
            selcv[base + off]   = coords4[p2];
        }
    }

    for (int idx = tid; idx < 4096; idx += 256) {
        int d = idx >> 6, c = idx & 63;
        wt_lds[c][d] = Wq1[idx];
    }
    if (tid < 64) bq_lds[tid] = bq1[tid];

    const float4* vf4 = reinterpret_cast<const float4*>(vfeat + (size_t)pt0 * 64);
    float4* out4 = reinterpret_cast<float4*>(out + (size_t)pt0 * 64);
    for (int idx = tid; idx < 1024; idx += 256) {
        float4 v = vf4[idx];
        out4[idx] = v;
        int r = idx >> 4, c4 = (idx & 15) * 4;
        *reinterpret_cast<float4*>(&vf_lds[r][c4]) = v;
    }
    __syncthreads();

    const int pl = tid >> 2;
    const int d0 = (tid & 3) * 16;
    float acc[16];
    #pragma unroll
    for (int i = 0; i < 16; i++) acc[i] = bq_lds[d0 + i];
    for (int k = 0; k < 64; k++) {
        float a = vf_lds[pl][k];
        const float4* wr = reinterpret_cast<const float4*>(&wt_lds[k][d0]);
        float4 w0 = wr[0], w1 = wr[1], w2 = wr[2], w3 = wr[3];
        acc[0]  += a * w0.x; acc[1]  += a * w0.y; acc[2]  += a * w0.z; acc[3]  += a * w0.w;
        acc[4]  += a * w1.x; acc[5]  += a * w1.y; acc[6]  += a * w1.z; acc[7]  += a * w1.w;
        acc[8]  += a * w2.x; acc[9]  += a * w2.y; acc[10] += a * w2.z; acc[11] += a * w2.w;
        acc[12] += a * w3.x; acc[13] += a * w3.y; acc[14] += a * w3.z; acc[15] += a * w3.w;
    }
    float4* q4 = reinterpret_cast<float4*>(q1s + (size_t)(pt0 + pl) * 64 + d0);
    #pragma unroll
    for (int j = 0; j < 4; j++) {
        q4[j] = make_float4(acc[4*j] * 0.125f, acc[4*j+1] * 0.125f,
                            acc[4*j+2] * 0.125f, acc[4*j+3] * 0.125f);
    }
}

// ---------------------------------------------------------------------------
// Kernel 2: dense sel-only attention (DPP reductions, readlane broadcasts,
// WEIGHT -> FINISH1 -> ISSUE(next) -> FINISH2 pipeline).  (unchanged)
// ---------------------------------------------------------------------------
__global__ __launch_bounds__(256) void attn_kernel(
    const uint32_t* __restrict__ km,
    const float* __restrict__ vfeat,
    const float* __restrict__ proj,
    const float* __restrict__ origins,
    const float* __restrict__ q1s,
    const float* __restrict__ Wq2, const float* __restrict__ bq2,
    const int*  __restrict__ sel_idx,
    const int4* __restrict__ selcv4,
    const int*  __restrict__ nsel_ptr,
    float* __restrict__ out)
{
    __shared__ __align__(16) float wq_lds[64 * 66];
    __shared__ __align__(16) float f_lds[4 * 64];
    __shared__ float bq_lds[64];
    __shared__ float proj_lds[B_ * N_ * 12];   // 216
    const int tid = threadIdx.x;

    for (int idx = tid; idx < 4096; idx += 256) {
        int d = idx >> 6, c = idx & 63;
        wq_lds[d * 66 + c] = Wq2[idx];
    }
    if (tid < 64) bq_lds[tid] = bq2[tid];
    if (tid < B_ * N_ * 12) proj_lds[tid] = proj[tid];
    __syncthreads();

    const int lane = tid & 63;
    const int wid  = tid >> 6;
    const int nw   = gridDim.x * 4;
    const int widG = blockIdx.x * 4 + wid;
    const int nsel = *nsel_ptr;

    if (widG >= nsel) return;

    const float o0x = origins[0], o0y = origins[1], o0z = origins[2];
    const float o1x = origins[3], o1y = origins[4], o1z = origins[5];

    uint32_t U[N_][4];
    float    kf1[N_], kf2[N_];
    int      packwI;  float fxI, fyI;
    int      pI;      float vfI, q1I;
    int      pC, vmC; float vfC, q1C;

    auto ISSUE = [&](int kk) {
        pI = sel_idx[kk];
        const int4 cv = selcv4[kk];
        const int  bi   = cv.w;
        const float wldx = (float)cv.x * 0.16f + (bi ? o1x : o0x);
        const float wldy = (float)cv.y * 0.16f + (bi ? o1y : o0y);
        const float wldz = (float)cv.z * 0.16f + (bi ? o1z : o0z);
        packwI = -1; fxI = 0.f; fyI = 0.f;
        if (lane < N_) {
            const float* Pr = &proj_lds[(bi * N_ + lane) * 12];
            float c0 = Pr[0]*wldx + Pr[1]*wldy + Pr[2]*wldz  + Pr[3];
            float c1 = Pr[4]*wldx + Pr[5]*wldy + Pr[6]*wldz  + Pr[7];
            float c2 = Pr[8]*wldx + Pr[9]*wldy + Pr[10]*wldz + Pr[11];
            float gx = 2.f * (c0 / c2) / (float)(W_ - 1) - 1.f;
            float gy = 2.f * (c1 / c2) / (float)(H_ - 1) - 1.f;
            if (fabsf(gx) <= 1.f && fabsf(gy) <= 1.f && c2 > 0.f) {
                float px = (gx + 1.f) * 0.5f * (float)(W_ - 1);
                float py = (gy + 1.f) * 0.5f * (float)(H_ - 1);
                float x0 = floorf(px), y0 = floorf(py);
                fxI = px - x0; fyI = py - y0;
                int x0i = (int)x0, y0i = (int)y0;
                int pb = ((bi * N_ + lane) * H_ + y0i) * W_ + x0i;
                packwI = pb | ((x0i < W_ - 1) ? (1 << 20) : 0)
                            | ((y0i < H_ - 1) ? (1 << 21) : 0);
            }
        }
        #pragma unroll
        for (int n = 0; n < N_; n++) {
            int pw = __builtin_amdgcn_readlane(packwI, n);   // uniform
            if (pw >= 0) {
                int pb  = pw & 0xFFFFF;
                int dxo = (pw & (1 << 20)) ? 64 : 0;
                int dyo = (pw & (1 << 21)) ? (W_ * 64) : 0;
                const uint32_t* kb = km + ((size_t)(unsigned)pb << 6);
                U[n][0] = kb[lane];
                U[n][1] = kb[lane + dxo];
                U[n][2] = kb[lane + dyo];
                U[n][3] = kb[lane + dyo + dxo];
            }
        }
        vfI = vfeat[(size_t)pI * 64 + lane];
        q1I = q1s[(size_t)pI * 64 + lane];
    };

    auto WEIGHT = [&]() {
        vmC = 0;
        #pragma unroll
        for (int n = 0; n < N_; n++) {
            int pw = __builtin_amdgcn_readlane(packwI, n);   // uniform
            if (pw >= 0) {
                vmC |= (1 << n);
                float wx = readlane_f(fxI, n), wy = readlane_f(fyI, n);
                float w11 = wx * wy;
                float w01 = wx - w11;
                float w10 = wy - w11;
                float w00 = 1.f - wx - wy + w11;
                kf1[n] = w00*bflo(U[n][0]) + w01*bflo(U[n][1]) + w10*bflo(U[n][2]) + w11*bflo(U[n][3]);
                kf2[n] = w00*bfhi(U[n][0]) + w01*bfhi(U[n][1]) + w10*bfhi(U[n][2]) + w11*bfhi(U[n][3]);
            } else { kf1[n] = 0.f; kf2[n] = 0.f; }
        }
        pC = pI; vfC = vfI; q1C = q1I;
    };

    auto FINISH1 = [&]() -> float {
        float l1[N_];
        #pragma unroll
        for (int n = 0; n < N_; n++)
            l1[n] = (vmC & (1 << n)) ? wave_sum64_dpp(q1C * kf1[n]) : NEG_;
        float mx = l1[0];
        #pragma unroll
        for (int n = 1; n < N_; n++) mx = fmaxf(mx, l1[n]);
        float ssum = 0.f, pr[N_];
        #pragma unroll
        for (int n = 0; n < N_; n++) { pr[n] = __expf(l1[n] - mx); ssum += pr[n]; }
        float inv = 1.f / ssum;
        float y1 = 0.f;
        #pragma unroll
        for (int n = 0; n < N_; n++) y1 += pr[n] * kf1[n];
        return vfC + y1 * inv;
    };

    auto FINISH2 = [&](float fcur) {
        f_lds[wid * 64 + lane] = fcur;
        float q2 = bq_lds[lane];
        {
            const float2* wrow = reinterpret_cast<const float2*>(&wq_lds[lane * 66]);
            const float2* fv   = reinterpret_cast<const float2*>(&f_lds[wid * 64]);
            #pragma unroll 8
            for (int cc = 0; cc < 32; cc++) {
                float2 w = wrow[cc]; float2 v = fv[cc];
                q2 += w.x * v.x + w.y * v.y;
            }
        }
        q2 *= 0.125f;

        float l2[N_];
        #pragma unroll
        for (int n = 0; n < N_; n++)
            l2[n] = (vmC & (1 << n)) ? wave_sum64_dpp(q2 * kf2[n]) : NEG_;
        float mx2 = l2[0];
        #pragma unroll
        for (int n = 1; n < N_; n++) mx2 = fmaxf(mx2, l2[n]);
        float ssum2 = 0.f, pr2[N_];
        #pragma unroll
        for (int n = 0; n < N_; n++) { pr2[n] = __expf(l2[n] - mx2); ssum2 += pr2[n]; }
        float inv2 = 1.f / ssum2;
        float y2 = 0.f;
        #pragma unroll
        for (int n = 0; n < N_; n++) y2 += pr2[n] * kf2[n];

        out[(size_t)pC * 64 + lane] = fcur + y2 * inv2;
    };

    int k = widG;
    ISSUE(k);
    while (true) {
        WEIGHT();
        float fcur = FINISH1();          // kf1 dead from here
        int kn = k + nw;
        if (kn < nsel) ISSUE(kn);        // next taps fly under FINISH2
        FINISH2(fcur);
        k = kn;
        if (k >= nsel) break;
    }
}

extern "C" void kernel_launch(void* const* d_in, const int* in_sizes, int n_in,
                              void* d_out, int out_size, void* d_ws, size_t ws_size,
                              hipStream_t stream) {
    const float* img    = (const float*)d_in[0];
    const int*   coords = (const int*)  d_in[1];
    const float* vf     = (const float*)d_in[2];
    const float* proj   = (const float*)d_in[3];
    const float* org    = (const float*)d_in[4];
    const int*   cm     = (const int*)  d_in[5];
    const float* Wq1    = (const float*)d_in[6];
    const float* bq1    = (const float*)d_in[7];
    const float* Wk1    = (const float*)d_in[8];
    const float* bk1    = (const float*)d_in[9];
    const float* Wq2    = (const float*)d_in[10];
    const float* bq2    = (const float*)d_in[11];
    const float* Wk2    = (const float*)d_in[12];
    const float* bk2    = (const float*)d_in[13];

    char* ws = (char*)d_ws;
    uint32_t* km      = (uint32_t*)(ws + OFF_KM);
    float*    q1s     = (float*)   (ws + OFF_Q1S);
    int4*     selcv   = (int4*)    (ws + OFF_SELCV);
    int*      sel_idx = (int*)     (ws + OFF_SELIX);
    int*      nsel    = (int*)     (ws + OFF_NSEL);
    float*    o       = (float*)d_out;

    hipMemsetAsync(nsel, 0, 4, stream);
    keymap_mfma_kernel<<<dim3(NPIX_ / 128), dim3(256), 0, stream>>>(img, Wk1, bk1, Wk2, bk2, km);
    qinit_kernel<<<dim3(P_ / 64), dim3(256), 0, stream>>>(
        vf, Wq1, bq1, cm, (const int4*)coords, q1s, o, sel_idx, selcv, nsel);
    attn_kernel<<<dim3(2048), dim3(256), 0, stream>>>(
        km, vf, proj, org, q1s, Wq2, bq2, sel_idx, selcv, nsel, o);
}

// Round 15
// 161.978 us; speedup vs baseline: 1.1083x; 1.1083x over previous
//
#include <hip/hip_runtime.h>
#include <hip/hip_bf16.h>
#include <stdint.h>

#define B_ 2
#define N_ 9
#define CB_ 80
#define H_ 120
#define W_ 160
#define D_ 64
#define P_ 80000
#define HW_ (H_*W_)        // 19200
#define NPIX_ (B_*N_*HW_)  // 345600
#define NEG_ (-10000.0f)

using short8 = __attribute__((ext_vector_type(8))) short;
using f32x4  = __attribute__((ext_vector_type(4))) float;

static __device__ __forceinline__ float bflo(uint32_t u) {
    return __uint_as_float(u << 16);
}
static __device__ __forceinline__ float bfhi(uint32_t u) {
    return __uint_as_float(u & 0xffff0000u);
}
// RNE float->bf16 bits (scalar fallback)
static __device__ __forceinline__ uint32_t f2bf_bits(float f) {
    uint32_t u = __float_as_uint(f);
    return (u + 0x7fffu + ((u >> 16) & 1u)) >> 16;
}
// HW packed conversion: dword = (bf16(lo), bf16(hi)), RNE — 1 instruction
static __device__ __forceinline__ uint32_t cvt_pk_bf16(float lo, float hi) {
    uint32_t r;
    asm("v_cvt_pk_bf16_f32 %0, %1, %2" : "=v"(r) : "v"(lo), "v"(hi));
    return r;
}

// 64-lane sum entirely on the VALU pipe (DPP), no DS ops.
static __device__ __forceinline__ float wave_sum64_dpp(float x) {
    float f = x;
    f += __int_as_float(__builtin_amdgcn_update_dpp(0, __float_as_int(f), 0x111, 0xF, 0xF, true));
    f += __int_as_float(__builtin_amdgcn_update_dpp(0, __float_as_int(f), 0x112, 0xF, 0xF, true));
    f += __int_as_float(__builtin_amdgcn_update_dpp(0, __float_as_int(f), 0x114, 0xF, 0xF, true));
    f += __int_as_float(__builtin_amdgcn_update_dpp(0, __float_as_int(f), 0x118, 0xF, 0xF, true));
    f += __int_as_float(__builtin_amdgcn_update_dpp(0, __float_as_int(f), 0x142, 0xA, 0xF, true));
    f += __int_as_float(__builtin_amdgcn_update_dpp(0, __float_as_int(f), 0x143, 0xC, 0xF, true));
    return __int_as_float(__builtin_amdgcn_readlane(__float_as_int(f), 63));  // uniform
}
static __device__ __forceinline__ float readlane_f(float v, int l) {
    return __int_as_float(__builtin_amdgcn_readlane(__float_as_int(v), l));
}

// ws layout (bytes)
#define OFF_KM    0
#define OFF_Q1S   ((size_t)NPIX_ * 64 * 4)                 // 88,473,600
#define OFF_SELCV (OFF_Q1S + (size_t)P_ * 64 * 4)          // +20,480,000
#define OFF_SELIX (OFF_SELCV + (size_t)P_ * 16)            // +1,280,000
#define OFF_NSEL  (OFF_SELIX + (size_t)P_ * 4)             // +320,000

// ---------------------------------------------------------------------------
// Kernel 1: key_maps via MFMA, v5.
//  - mi-split: two sequential pixel-half passes -> acc only 32 VGPR/pass,
//    BOTH sets live per pass -> packed-dword stores (no RMW; R14's WRITE
//    explosion fixed)
//  - B-frags reloaded per k-chunk from L2-hot weights (no 48-reg residency)
//  - all f32->bf16 via v_cvt_pk_bf16_f32 (1 op / 2 elems)
// Target VGPR ~72-80 -> 6 waves/SIMD; LDS 26.6 KB -> 6 blocks/CU cap.
// ---------------------------------------------------------------------------
__global__ __launch_bounds__(256) void keymap_mfma_kernel(
    const float* __restrict__ img,
    const float* __restrict__ Wk1, const float* __restrict__ bk1,
    const float* __restrict__ Wk2, const float* __restrict__ bk2,
    uint32_t* __restrict__ km)
{
    // row stride 104 bf16 = 208 B = 13*16 B: b128-aligned; rows 0..7 cover all
    // 32 banks exactly once -> b128 read/write at the bank floor
    __shared__ short a_lds[128][104];   // a[px][k] (bf16 bits), 26.6 KB
    const int tid  = threadIdx.x;
    const int lane = tid & 63;
    const int wv   = tid >> 6;
    const int lr   = lane & 15;
    const int lg   = lane >> 4;
    const int dw   = (wv >> 1) * 32;     // wave's d half
    const int pxw  = (wv & 1) * 64;      // wave's pixel half

    // ---- A tile -> LDS: thread owns (px, k-octet); b128 writes, cvt_pk ----
    const int pix0 = blockIdx.x * 128;
    const int bn   = pix0 / HW_;
    const int hw0  = pix0 - bn * HW_;
    const float* ibase = img + (size_t)bn * CB_ * HW_ + hw0;
    {
        const int px = tid & 127;
        const int kh = (tid >> 7) * 48;          // 0 or 48
        #pragma unroll
        for (int oct = 0; oct < 6; oct++) {
            const int k = kh + oct * 8;
            uint32_t w0 = 0, w1 = 0, w2 = 0, w3 = 0;
            if (k < 80) {
                float e0 = ibase[(k + 0) * HW_ + px], e1 = ibase[(k + 1) * HW_ + px];
                float e2 = ibase[(k + 2) * HW_ + px], e3 = ibase[(k + 3) * HW_ + px];
                float e4 = ibase[(k + 4) * HW_ + px], e5 = ibase[(k + 5) * HW_ + px];
                float e6 = ibase[(k + 6) * HW_ + px], e7 = ibase[(k + 7) * HW_ + px];
                w0 = cvt_pk_bf16(e0, e1); w1 = cvt_pk_bf16(e2, e3);
                w2 = cvt_pk_bf16(e4, e5); w3 = cvt_pk_bf16(e6, e7);
            }
            uint4 v = make_uint4(w0, w1, w2, w3);
            *reinterpret_cast<uint4*>(&a_lds[px][k]) = v;
        }
    }
    __syncthreads();

    const int kq = lg * 8;   // this lane's k-octet base within a chunk

    #pragma unroll 1                 // keep pixel-half passes SEQUENTIAL
    for (int half = 0; half < 2; half++) {
        const int pxh = pxw + half * 32;   // this pass covers pxh .. pxh+31

        f32x4 acc1[2][2], acc2[2][2];      // [mi2][ni], 32 VGPR total
        #pragma unroll
        for (int mi = 0; mi < 2; mi++)
            #pragma unroll
            for (int ni = 0; ni < 2; ni++) {
                acc1[mi][ni] = (f32x4){0.f, 0.f, 0.f, 0.f};
                acc2[mi][ni] = (f32x4){0.f, 0.f, 0.f, 0.f};
            }

        #pragma unroll
        for (int kc = 0; kc < 3; kc++) {
            const int k0 = kc * 32;
            const int k  = k0 + kq;
            // B frags for this k-chunk (L2-hot), transient
            short8 bv1[2], bv2[2];
            #pragma unroll
            for (int ni = 0; ni < 2; ni++) {
                const int d = dw + ni * 16 + lr;
                short8 v1 = {0,0,0,0,0,0,0,0}, v2 = {0,0,0,0,0,0,0,0};
                if (k < 80) {
                    const float4* p1 = reinterpret_cast<const float4*>(Wk1 + d * 80 + k);
                    const float4* p2 = reinterpret_cast<const float4*>(Wk2 + d * 80 + k);
                    float4 a0 = p1[0], a1 = p1[1];
                    float4 c0 = p2[0], c1 = p2[1];
                    uint4 u1 = make_uint4(cvt_pk_bf16(a0.x, a0.y), cvt_pk_bf16(a0.z, a0.w),
                                          cvt_pk_bf16(a1.x, a1.y), cvt_pk_bf16(a1.z, a1.w));
                    uint4 u2 = make_uint4(cvt_pk_bf16(c0.x, c0.y), cvt_pk_bf16(c0.z, c0.w),
                                          cvt_pk_bf16(c1.x, c1.y), cvt_pk_bf16(c1.z, c1.w));
                    v1 = *reinterpret_cast<short8*>(&u1);
                    v2 = *reinterpret_cast<short8*>(&u2);
                }
                bv1[ni] = v1; bv2[ni] = v2;
            }
            #pragma unroll
            for (int mi = 0; mi < 2; mi++) {
                short8 av = *reinterpret_cast<const short8*>(
                    &a_lds[pxh + mi * 16 + lr][k0 + kq]);
                acc1[mi][0] = __builtin_amdgcn_mfma_f32_16x16x32_bf16(av, bv1[0], acc1[mi][0], 0, 0, 0);
                acc1[mi][1] = __builtin_amdgcn_mfma_f32_16x16x32_bf16(av, bv1[1], acc1[mi][1], 0, 0, 0);
                acc2[mi][0] = __builtin_amdgcn_mfma_f32_16x16x32_bf16(av, bv2[0], acc2[mi][0], 0, 0, 0);
                acc2[mi][1] = __builtin_amdgcn_mfma_f32_16x16x32_bf16(av, bv2[1], acc2[mi][1], 0, 0, 0);
            }
        }

        // epilogue: add bias, pack (set1,set2) -> one dword, coalesced stores
        #pragma unroll
        for (int ni = 0; ni < 2; ni++) {
            const int d = dw + ni * 16 + lr;
            const float b1 = bk1[d], b2 = bk2[d];
            #pragma unroll
            for (int mi = 0; mi < 2; mi++) {
                #pragma unroll
                for (int r = 0; r < 4; r++) {
                    int pix = pix0 + pxh + mi * 16 + lg * 4 + r;
                    km[(size_t)pix * 64 + d] =
                        cvt_pk_bf16(acc1[mi][ni][r] + b1, acc2[mi][ni][r] + b2);
                }
            }
        }
    }
}

// ---------------------------------------------------------------------------
// Kernel 1b: q1 prepass + out-init + SEL COMPACTION.  (unchanged)
// ---------------------------------------------------------------------------
__global__ __launch_bounds__(256) void qinit_kernel(
    const float* __restrict__ vfeat,
    const float* __restrict__ Wq1, const float* __restrict__ bq1,
    const int*   __restrict__ cmask,
    const int4*  __restrict__ coords4,
    float* __restrict__ q1s, float* __restrict__ out,
    int* __restrict__ sel_idx, int4* __restrict__ selcv, int* __restrict__ nsel)
{
    __shared__ float wt_lds[64][68];   // wt[c][d] = Wq1[d][c], padded
    __shared__ float vf_lds[64][68];
    __shared__ float bq_lds[64];
    const int tid = threadIdx.x;
    const int pt0 = blockIdx.x * 64;

    if (tid < 64) {
        int p2 = pt0 + tid;
        bool s = cmask[p2] > 1;
        unsigned long long m = __ballot(s);
        int base = 0;
        if (tid == 0 && m) base = atomicAdd(nsel, __popcll(m));
        base = __shfl(base, 0);
        if (s) {
            int off = __popcll(m & ((1ull << tid) - 1ull));
            sel_idx[base + off] = p2;
            selcv[base + off]   = coords4[p2];
        }
    }

    for (int idx = tid; idx < 4096; idx += 256) {
        int d = idx >> 6, c = idx & 63;
        wt_lds[c][d] = Wq1[idx];
    }
    if (tid < 64) bq_lds[tid] = bq1[tid];

    const float4* vf4 = reinterpret_cast<const float4*>(vfeat + (size_t)pt0 * 64);
    float4* out4 = reinterpret_cast<float4*>(out + (size_t)pt0 * 64);
    for (int idx = tid; idx < 1024; idx += 256) {
        float4 v = vf4[idx];
        out4[idx] = v;
        int r = idx >> 4, c4 = (idx & 15) * 4;
        *reinterpret_cast<float4*>(&vf_lds[r][c4]) = v;
    }
    __syncthreads();

    const int pl = tid >> 2;
    const int d0 = (tid & 3) * 16;
    float acc[16];
    #pragma unroll
    for (int i = 0; i < 16; i++) acc[i] = bq_lds[d0 + i];
    for (int k = 0; k < 64; k++) {
        float a = vf_lds[pl][k];
        const float4* wr = reinterpret_cast<const float4*>(&wt_lds[k][d0]);
        float4 w0 = wr[0], w1 = wr[1], w2 = wr[2], w3 = wr[3];
        acc[0]  += a * w0.x; acc[1]  += a * w0.y; acc[2]  += a * w0.z; acc[3]  += a * w0.w;
        acc[4]  += a * w1.x; acc[5]  += a * w1.y; acc[6]  += a * w1.z; acc[7]  += a * w1.w;
        acc[8]  += a * w2.x; acc[9]  += a * w2.y; acc[10] += a * w2.z; acc[11] += a * w2.w;
        acc[12] += a * w3.x; acc[13] += a * w3.y; acc[14] += a * w3.z; acc[15] += a * w3.w;
    }
    float4* q4 = reinterpret_cast<float4*>(q1s + (size_t)(pt0 + pl) * 64 + d0);
    #pragma unroll
    for (int j = 0; j < 4; j++) {
        q4[j] = make_float4(acc[4*j] * 0.125f, acc[4*j+1] * 0.125f,
                            acc[4*j+2] * 0.125f, acc[4*j+3] * 0.125f);
    }
}

// ---------------------------------------------------------------------------
// Kernel 2: dense sel-only attention (DPP reductions, readlane broadcasts,
// WEIGHT -> FINISH1 -> ISSUE(next) -> FINISH2 pipeline).  (unchanged, R13)
// ---------------------------------------------------------------------------
__global__ __launch_bounds__(256) void attn_kernel(
    const uint32_t* __restrict__ km,
    const float* __restrict__ vfeat,
    const float* __restrict__ proj,
    const float* __restrict__ origins,
    const float* __restrict__ q1s,
    const float* __restrict__ Wq2, const float* __restrict__ bq2,
    const int*  __restrict__ sel_idx,
    const int4* __restrict__ selcv4,
    const int*  __restrict__ nsel_ptr,
    float* __restrict__ out)
{
    __shared__ __align__(16) float wq_lds[64 * 66];
    __shared__ __align__(16) float f_lds[4 * 64];
    __shared__ float bq_lds[64];
    __shared__ float proj_lds[B_ * N_ * 12];   // 216
    const int tid = threadIdx.x;

    for (int idx = tid; idx < 4096; idx += 256) {
        int d = idx >> 6, c = idx & 63;
        wq_lds[d * 66 + c] = Wq2[idx];
    }
    if (tid < 64) bq_lds[tid] = bq2[tid];
    if (tid < B_ * N_ * 12) proj_lds[tid] = proj[tid];
    __syncthreads();

    const int lane = tid & 63;
    const int wid  = tid >> 6;
    const int nw   = gridDim.x * 4;
    const int widG = blockIdx.x * 4 + wid;
    const int nsel = *nsel_ptr;

    if (widG >= nsel) return;

    const float o0x = origins[0], o0y = origins[1], o0z = origins[2];
    const float o1x = origins[3], o1y = origins[4], o1z = origins[5];

    uint32_t U[N_][4];
    float    kf1[N_], kf2[N_];
    int      packwI;  float fxI, fyI;
    int      pI;      float vfI, q1I;
    int      pC, vmC; float vfC, q1C;

    auto ISSUE = [&](int kk) {
        pI = sel_idx[kk];
        const int4 cv = selcv4[kk];
        const int  bi   = cv.w;
        const float wldx = (float)cv.x * 0.16f + (bi ? o1x : o0x);
        const float wldy = (float)cv.y * 0.16f + (bi ? o1y : o0y);
        const float wldz = (float)cv.z * 0.16f + (bi ? o1z : o0z);
        packwI = -1; fxI = 0.f; fyI = 0.f;
        if (lane < N_) {
            const float* Pr = &proj_lds[(bi * N_ + lane) * 12];
            float c0 = Pr[0]*wldx + Pr[1]*wldy + Pr[2]*wldz  + Pr[3];
            float c1 = Pr[4]*wldx + Pr[5]*wldy + Pr[6]*wldz  + Pr[7];
            float c2 = Pr[8]*wldx + Pr[9]*wldy + Pr[10]*wldz + Pr[11];
            float gx = 2.f * (c0 / c2) / (float)(W_ - 1) - 1.f;
            float gy = 2.f * (c1 / c2) / (float)(H_ - 1) - 1.f;
            if (fabsf(gx) <= 1.f && fabsf(gy) <= 1.f && c2 > 0.f) {
                float px = (gx + 1.f) * 0.5f * (float)(W_ - 1);
                float py = (gy + 1.f) * 0.5f * (float)(H_ - 1);
                float x0 = floorf(px), y0 = floorf(py);
                fxI = px - x0; fyI = py - y0;
                int x0i = (int)x0, y0i = (int)y0;
                int pb = ((bi * N_ + lane) * H_ + y0i) * W_ + x0i;
                packwI = pb | ((x0i < W_ - 1) ? (1 << 20) : 0)
                            | ((y0i < H_ - 1) ? (1 << 21) : 0);
            }
        }
        #pragma unroll
        for (int n = 0; n < N_; n++) {
            int pw = __builtin_amdgcn_readlane(packwI, n);   // uniform
            if (pw >= 0) {
                int pb  = pw & 0xFFFFF;
                int dxo = (pw & (1 << 20)) ? 64 : 0;
                int dyo = (pw & (1 << 21)) ? (W_ * 64) : 0;
                const uint32_t* kb = km + ((size_t)(unsigned)pb << 6);
                U[n][0] = kb[lane];
                U[n][1] = kb[lane + dxo];
                U[n][2] = kb[lane + dyo];
                U[n][3] = kb[lane + dyo + dxo];
            }
        }
        vfI = vfeat[(size_t)pI * 64 + lane];
        q1I = q1s[(size_t)pI * 64 + lane];
    };

    auto WEIGHT = [&]() {
        vmC = 0;
        #pragma unroll
        for (int n = 0; n < N_; n++) {
            int pw = __builtin_amdgcn_readlane(packwI, n);   // uniform
            if (pw >= 0) {
                vmC |= (1 << n);
                float wx = readlane_f(fxI, n), wy = readlane_f(fyI, n);
                float w11 = wx * wy;
                float w01 = wx - w11;
                float w10 = wy - w11;
                float w00 = 1.f - wx - wy + w11;
                kf1[n] = w00*bflo(U[n][0]) + w01*bflo(U[n][1]) + w10*bflo(U[n][2]) + w11*bflo(U[n][3]);
                kf2[n] = w00*bfhi(U[n][0]) + w01*bfhi(U[n][1]) + w10*bfhi(U[n][2]) + w11*bfhi(U[n][3]);
            } else { kf1[n] = 0.f; kf2[n] = 0.f; }
        }
        pC = pI; vfC = vfI; q1C = q1I;
    };

    auto FINISH1 = [&]() -> float {
        float l1[N_];
        #pragma unroll
        for (int n = 0; n < N_; n++)
            l1[n] = (vmC & (1 << n)) ? wave_sum64_dpp(q1C * kf1[n]) : NEG_;
        float mx = l1[0];
        #pragma unroll
        for (int n = 1; n < N_; n++) mx = fmaxf(mx, l1[n]);
        float ssum = 0.f, pr[N_];
        #pragma unroll
        for (int n = 0; n < N_; n++) { pr[n] = __expf(l1[n] - mx); ssum += pr[n]; }
        float inv = 1.f / ssum;
        float y1 = 0.f;
        #pragma unroll
        for (int n = 0; n < N_; n++) y1 += pr[n] * kf1[n];
        return vfC + y1 * inv;
    };

    auto FINISH2 = [&](float fcur) {
        f_lds[wid * 64 + lane] = fcur;
        float q2 = bq_lds[lane];
        {
            const float2* wrow = reinterpret_cast<const float2*>(&wq_lds[lane * 66]);
            const float2* fv   = reinterpret_cast<const float2*>(&f_lds[wid * 64]);
            #pragma unroll 8
            for (int cc = 0; cc < 32; cc++) {
                float2 w = wrow[cc]; float2 v = fv[cc];
                q2 += w.x * v.x + w.y * v.y;
            }
        }
        q2 *= 0.125f;

        float l2[N_];
        #pragma unroll
        for (int n = 0; n < N_; n++)
            l2[n] = (vmC & (1 << n)) ? wave_sum64_dpp(q2 * kf2[n]) : NEG_;
        float mx2 = l2[0];
        #pragma unroll
        for (int n = 1; n < N_; n++) mx2 = fmaxf(mx2, l2[n]);
        float ssum2 = 0.f, pr2[N_];
        #pragma unroll
        for (int n = 0; n < N_; n++) { pr2[n] = __expf(l2[n] - mx2); ssum2 += pr2[n]; }
        float inv2 = 1.f / ssum2;
        float y2 = 0.f;
        #pragma unroll
        for (int n = 0; n < N_; n++) y2 += pr2[n] * kf2[n];

        out[(size_t)pC * 64 + lane] = fcur + y2 * inv2;
    };

    int k = widG;
    ISSUE(k);
    while (true) {
        WEIGHT();
        float fcur = FINISH1();          // kf1 dead from here
        int kn = k + nw;
        if (kn < nsel) ISSUE(kn);        // next taps fly under FINISH2
        FINISH2(fcur);
        k = kn;
        if (k >= nsel) break;
    }
}

extern "C" void kernel_launch(void* const* d_in, const int* in_sizes, int n_in,
                              void* d_out, int out_size, void* d_ws, size_t ws_size,
                              hipStream_t stream) {
    const float* img    = (const float*)d_in[0];
    const int*   coords = (const int*)  d_in[1];
    const float* vf     = (const float*)d_in[2];
    const float* proj   = (const float*)d_in[3];
    const float* org    = (const float*)d_in[4];
    const int*   cm     = (const int*)  d_in[5];
    const float* Wq1    = (const float*)d_in[6];
    const float* bq1    = (const float*)d_in[7];
    const float* Wk1    = (const float*)d_in[8];
    const float* bk1    = (const float*)d_in[9];
    const float* Wq2    = (const float*)d_in[10];
    const float* bq2    = (const float*)d_in[11];
    const float* Wk2    = (const float*)d_in[12];
    const float* bk2    = (const float*)d_in[13];

    char* ws = (char*)d_ws;
    uint32_t* km      = (uint32_t*)(ws + OFF_KM);
    float*    q1s     = (float*)   (ws + OFF_Q1S);
    int4*     selcv   = (int4*)    (ws + OFF_SELCV);
    int*      sel_idx = (int*)     (ws + OFF_SELIX);
    int*      nsel    = (int*)     (ws + OFF_NSEL);
    float*    o       = (float*)d_out;

    hipMemsetAsync(nsel, 0, 4, stream);
    keymap_mfma_kernel<<<dim3(NPIX_ / 128), dim3(256), 0, stream>>>(img, Wk1, bk1, Wk2, bk2, km);
    qinit_kernel<<<dim3(P_ / 64), dim3(256), 0, stream>>>(
        vf, Wq1, bq1, cm, (const int4*)coords, q1s, o, sel_idx, selcv, nsel);
    attn_kernel<<<dim3(2048), dim3(256), 0, stream>>>(
        km, vf, proj, org, q1s, Wq2, bq2, sel_idx, selcv, nsel, o);
}

// Round 16
// 156.660 us; speedup vs baseline: 1.1459x; 1.0339x over previous
//
#include <hip/hip_runtime.h>
#include <hip/hip_bf16.h>
#include <stdint.h>

#define B_ 2
#define N_ 9
#define CB_ 80
#define H_ 120
#define W_ 160
#define D_ 64
#define P_ 80000
#define HW_ (H_*W_)        // 19200
#define NPIX_ (B_*N_*HW_)  // 345600
#define NEG_ (-10000.0f)

using short8 = __attribute__((ext_vector_type(8))) short;
using f32x4  = __attribute__((ext_vector_type(4))) float;

static __device__ __forceinline__ float bflo(uint32_t u) {
    return __uint_as_float(u << 16);
}
static __device__ __forceinline__ float bfhi(uint32_t u) {
    return __uint_as_float(u & 0xffff0000u);
}
// RNE float->bf16 bits (scalar fallback)
static __device__ __forceinline__ uint32_t f2bf_bits(float f) {
    uint32_t u = __float_as_uint(f);
    return (u + 0x7fffu + ((u >> 16) & 1u)) >> 16;
}
// HW packed conversion: dword = (bf16(lo), bf16(hi)), RNE — 1 instruction
static __device__ __forceinline__ uint32_t cvt_pk_bf16(float lo, float hi) {
    uint32_t r;
    asm("v_cvt_pk_bf16_f32 %0, %1, %2" : "=v"(r) : "v"(lo), "v"(hi));
    return r;
}

// 64-lane sum entirely on the VALU pipe (DPP), no DS ops.
static __device__ __forceinline__ float wave_sum64_dpp(float x) {
    float f = x;
    f += __int_as_float(__builtin_amdgcn_update_dpp(0, __float_as_int(f), 0x111, 0xF, 0xF, true));
    f += __int_as_float(__builtin_amdgcn_update_dpp(0, __float_as_int(f), 0x112, 0xF, 0xF, true));
    f += __int_as_float(__builtin_amdgcn_update_dpp(0, __float_as_int(f), 0x114, 0xF, 0xF, true));
    f += __int_as_float(__builtin_amdgcn_update_dpp(0, __float_as_int(f), 0x118, 0xF, 0xF, true));
    f += __int_as_float(__builtin_amdgcn_update_dpp(0, __float_as_int(f), 0x142, 0xA, 0xF, true));
    f += __int_as_float(__builtin_amdgcn_update_dpp(0, __float_as_int(f), 0x143, 0xC, 0xF, true));
    return __int_as_float(__builtin_amdgcn_readlane(__float_as_int(f), 63));  // uniform
}
static __device__ __forceinline__ float readlane_f(float v, int l) {
    return __int_as_float(__builtin_amdgcn_readlane(__float_as_int(v), l));
}

// ws layout (bytes)
#define OFF_KM    0
#define OFF_Q1S   ((size_t)NPIX_ * 64 * 4)                 // 88,473,600
#define OFF_SELCV (OFF_Q1S + (size_t)P_ * 64 * 4)          // +20,480,000
#define OFF_SELIX (OFF_SELCV + (size_t)P_ * 16)            // +1,280,000
#define OFF_NSEL  (OFF_SELIX + (size_t)P_ * 4)             // +320,000

// ---------------------------------------------------------------------------
// Kernel 1: key_maps via MFMA — REVERT to R9 v2 structure (measured ~55 us):
//  - W fragments preloaded ONCE into registers BEFORE A-staging (their L2
//    latency hides under the A-tile global loads); single compute pass with
//    both accumulator banks live; packed-dword stores.
//  - only change vs R9: v_cvt_pk_bf16_f32 for all f32->bf16 (R15-proven).
// ---------------------------------------------------------------------------
__global__ __launch_bounds__(256) void keymap_mfma_kernel(
    const float* __restrict__ img,
    const float* __restrict__ Wk1, const float* __restrict__ bk1,
    const float* __restrict__ Wk2, const float* __restrict__ bk2,
    uint32_t* __restrict__ km)
{
    // row stride 104 bf16 = 208 B = 13*16 B: b128-aligned; rows 0..7 cover all
    // 32 banks exactly once -> b128 read/write at the bank floor
    __shared__ short a_lds[128][104];   // a[px][k] (bf16 bits), 26.6 KB
    const int tid  = threadIdx.x;
    const int lane = tid & 63;
    const int wv   = tid >> 6;
    const int lr   = lane & 15;
    const int lg   = lane >> 4;
    const int dw   = (wv >> 1) * 32;     // wave's d half
    const int pxw  = (wv & 1) * 64;      // wave's pixel half

    // ---- W fragments -> registers (once; L2-hot; hidden under A staging) ----
    short8 bf1[3][2], bf2[3][2];
    #pragma unroll
    for (int kc = 0; kc < 3; kc++) {
        const int k = kc * 32 + lg * 8;
        #pragma unroll
        for (int ni = 0; ni < 2; ni++) {
            const int d = dw + ni * 16 + lr;
            short8 v1 = {0,0,0,0,0,0,0,0}, v2 = {0,0,0,0,0,0,0,0};
            if (k < 80) {
                const float4* p1 = reinterpret_cast<const float4*>(Wk1 + d * 80 + k);
                const float4* p2 = reinterpret_cast<const float4*>(Wk2 + d * 80 + k);
                float4 a0 = p1[0], a1 = p1[1];
                float4 c0 = p2[0], c1 = p2[1];
                uint4 u1 = make_uint4(cvt_pk_bf16(a0.x, a0.y), cvt_pk_bf16(a0.z, a0.w),
                                      cvt_pk_bf16(a1.x, a1.y), cvt_pk_bf16(a1.z, a1.w));
                uint4 u2 = make_uint4(cvt_pk_bf16(c0.x, c0.y), cvt_pk_bf16(c0.z, c0.w),
                                      cvt_pk_bf16(c1.x, c1.y), cvt_pk_bf16(c1.z, c1.w));
                v1 = *reinterpret_cast<short8*>(&u1);
                v2 = *reinterpret_cast<short8*>(&u2);
            }
            bf1[kc][ni] = v1; bf2[kc][ni] = v2;
        }
    }

    // ---- A tile -> LDS: thread owns (px, k-octet); b128 writes, cvt_pk ----
    const int pix0 = blockIdx.x * 128;
    const int bn   = pix0 / HW_;
    const int hw0  = pix0 - bn * HW_;
    const float* ibase = img + (size_t)bn * CB_ * HW_ + hw0;
    {
        const int px = tid & 127;
        const int kh = (tid >> 7) * 48;          // 0 or 48
        #pragma unroll
        for (int oct = 0; oct < 6; oct++) {
            const int k = kh + oct * 8;
            uint32_t w0 = 0, w1 = 0, w2 = 0, w3 = 0;
            if (k < 80) {
                float e0 = ibase[(k + 0) * HW_ + px], e1 = ibase[(k + 1) * HW_ + px];
                float e2 = ibase[(k + 2) * HW_ + px], e3 = ibase[(k + 3) * HW_ + px];
                float e4 = ibase[(k + 4) * HW_ + px], e5 = ibase[(k + 5) * HW_ + px];
                float e6 = ibase[(k + 6) * HW_ + px], e7 = ibase[(k + 7) * HW_ + px];
                w0 = cvt_pk_bf16(e0, e1); w1 = cvt_pk_bf16(e2, e3);
                w2 = cvt_pk_bf16(e4, e5); w3 = cvt_pk_bf16(e6, e7);
            }
            uint4 v = make_uint4(w0, w1, w2, w3);
            *reinterpret_cast<uint4*>(&a_lds[px][k]) = v;
        }
    }
    __syncthreads();

    f32x4 acc1[4][2], acc2[4][2];
    #pragma unroll
    for (int mi = 0; mi < 4; mi++)
        #pragma unroll
        for (int ni = 0; ni < 2; ni++) {
            acc1[mi][ni] = (f32x4){0.f, 0.f, 0.f, 0.f};
            acc2[mi][ni] = (f32x4){0.f, 0.f, 0.f, 0.f};
        }

    #pragma unroll
    for (int kc = 0; kc < 3; kc++) {
        const int k0 = kc * 32;
        short8 av[4];
        #pragma unroll
        for (int mi = 0; mi < 4; mi++)
            av[mi] = *reinterpret_cast<const short8*>(&a_lds[pxw + mi * 16 + lr][k0 + lg * 8]);
        #pragma unroll
        for (int mi = 0; mi < 4; mi++) {
            #pragma unroll
            for (int ni = 0; ni < 2; ni++) {
                acc1[mi][ni] = __builtin_amdgcn_mfma_f32_16x16x32_bf16(av[mi], bf1[kc][ni], acc1[mi][ni], 0, 0, 0);
                acc2[mi][ni] = __builtin_amdgcn_mfma_f32_16x16x32_bf16(av[mi], bf2[kc][ni], acc2[mi][ni], 0, 0, 0);
            }
        }
    }

    // epilogue: add bias, pack (set1,set2) -> one dword, coalesced stores
    #pragma unroll
    for (int ni = 0; ni < 2; ni++) {
        const int d = dw + ni * 16 + lr;
        const float b1 = bk1[d], b2 = bk2[d];
        #pragma unroll
        for (int mi = 0; mi < 4; mi++) {
            #pragma unroll
            for (int r = 0; r < 4; r++) {
                int pix = pix0 + pxw + mi * 16 + lg * 4 + r;
                km[(size_t)pix * 64 + d] = cvt_pk_bf16(acc1[mi][ni][r] + b1, acc2[mi][ni][r] + b2);
            }
        }
    }
}

// ---------------------------------------------------------------------------
// Kernel 1b: q1 prepass + out-init + SEL COMPACTION.  (unchanged)
// ---------------------------------------------------------------------------
__global__ __launch_bounds__(256) void qinit_kernel(
    const float* __restrict__ vfeat,
    const float* __restrict__ Wq1, const float* __restrict__ bq1,
    const int*   __restrict__ cmask,
    const int4*  __restrict__ coords4,
    float* __restrict__ q1s, float* __restrict__ out,
    int* __restrict__ sel_idx, int4* __restrict__ selcv, int* __restrict__ nsel)
{
    __shared__ float wt_lds[64][68];   // wt[c][d] = Wq1[d][c], padded
    __shared__ float vf_lds[64][68];
    __shared__ float bq_lds[64];
    const int tid = threadIdx.x;
    const int pt0 = blockIdx.x * 64;

    if (tid < 64) {
        int p2 = pt0 + tid;
        bool s = cmask[p2] > 1;
        unsigned long long m = __ballot(s);
        int base = 0;
        if (tid == 0 && m) base = atomicAdd(nsel, __popcll(m));
        base = __shfl(base, 0);
        if (s) {
            int off = __popcll(m & ((1ull << tid) - 1ull));
            sel_idx[base + off] = p2;
            selcv[base + off]   = coords4[p2];
        }
    }

    for (int idx = tid; idx < 4096; idx += 256) {
        int d = idx >> 6, c = idx & 63;
        wt_lds[c][d] = Wq1[idx];
    }
    if (tid < 64) bq_lds[tid] = bq1[tid];

    const float4* vf4 = reinterpret_cast<const float4*>(vfeat + (size_t)pt0 * 64);
    float4* out4 = reinterpret_cast<float4*>(out + (size_t)pt0 * 64);
    for (int idx = tid; idx < 1024; idx += 256) {
        float4 v = vf4[idx];
        out4[idx] = v;
        int r = idx >> 4, c4 = (idx & 15) * 4;
        *reinterpret_cast<float4*>(&vf_lds[r][c4]) = v;
    }
    __syncthreads();

    const int pl = tid >> 2;
    const int d0 = (tid & 3) * 16;
    float acc[16];
    #pragma unroll
    for (int i = 0; i < 16; i++) acc[i] = bq_lds[d0 + i];
    for (int k = 0; k < 64; k++) {
        float a = vf_lds[pl][k];
        const float4* wr = reinterpret_cast<const float4*>(&wt_lds[k][d0]);
        float4 w0 = wr[0], w1 = wr[1], w2 = wr[2], w3 = wr[3];
        acc[0]  += a * w0.x; acc[1]  += a * w0.y; acc[2]  += a * w0.z; acc[3]  += a * w0.w;
        acc[4]  += a * w1.x; acc[5]  += a * w1.y; acc[6]  += a * w1.z; acc[7]  += a * w1.w;
        acc[8]  += a * w2.x; acc[9]  += a * w2.y; acc[10] += a * w2.z; acc[11] += a * w2.w;
        acc[12] += a * w3.x; acc[13] += a * w3.y; acc[14] += a * w3.z; acc[15] += a * w3.w;
    }
    float4* q4 = reinterpret_cast<float4*>(q1s + (size_t)(pt0 + pl) * 64 + d0);
    #pragma unroll
    for (int j = 0; j < 4; j++) {
        q4[j] = make_float4(acc[4*j] * 0.125f, acc[4*j+1] * 0.125f,
                            acc[4*j+2] * 0.125f, acc[4*j+3] * 0.125f);
    }
}

// ---------------------------------------------------------------------------
// Kernel 2: dense sel-only attention (DPP reductions, readlane broadcasts,
// WEIGHT -> FINISH1 -> ISSUE(next) -> FINISH2 pipeline).  (unchanged, R13)
// ---------------------------------------------------------------------------
__global__ __launch_bounds__(256) void attn_kernel(
    const uint32_t* __restrict__ km,
    const float* __restrict__ vfeat,
    const float* __restrict__ proj,
    const float* __restrict__ origins,
    const float* __restrict__ q1s,
    const float* __restrict__ Wq2, const float* __restrict__ bq2,
    const int*  __restrict__ sel_idx,
    const int4* __restrict__ selcv4,
    const int*  __restrict__ nsel_ptr,
    float* __restrict__ out)
{
    __shared__ __align__(16) float wq_lds[64 * 66];
    __shared__ __align__(16) float f_lds[4 * 64];
    __shared__ float bq_lds[64];
    __shared__ float proj_lds[B_ * N_ * 12];   // 216
    const int tid = threadIdx.x;

    for (int idx = tid; idx < 4096; idx += 256) {
        int d = idx >> 6, c = idx & 63;
        wq_lds[d * 66 + c] = Wq2[idx];
    }
    if (tid < 64) bq_lds[tid] = bq2[tid];
    if (tid < B_ * N_ * 12) proj_lds[tid] = proj[tid];
    __syncthreads();

    const int lane = tid & 63;
    const int wid  = tid >> 6;
    const int nw   = gridDim.x * 4;
    const int widG = blockIdx.x * 4 + wid;
    const int nsel = *nsel_ptr;

    if (widG >= nsel) return;

    const float o0x = origins[0], o0y = origins[1], o0z = origins[2];
    const float o1x = origins[3], o1y = origins[4], o1z = origins[5];

    uint32_t U[N_][4];
    float    kf1[N_], kf2[N_];
    int      packwI;  float fxI, fyI;
    int      pI;      float vfI, q1I;
    int      pC, vmC; float vfC, q1C;

    auto ISSUE = [&](int kk) {
        pI = sel_idx[kk];
        const int4 cv = selcv4[kk];
        const int  bi   = cv.w;
        const float wldx = (float)cv.x * 0.16f + (bi ? o1x : o0x);
        const float wldy = (float)cv.y * 0.16f + (bi ? o1y : o0y);
        const float wldz = (float)cv.z * 0.16f + (bi ? o1z : o0z);
        packwI = -1; fxI = 0.f; fyI = 0.f;
        if (lane < N_) {
            const float* Pr = &proj_lds[(bi * N_ + lane) * 12];
            float c0 = Pr[0]*wldx + Pr[1]*wldy + Pr[2]*wldz  + Pr[3];
            float c1 = Pr[4]*wldx + Pr[5]*wldy + Pr[6]*wldz  + Pr[7];
            float c2 = Pr[8]*wldx + Pr[9]*wldy + Pr[10]*wldz + Pr[11];
            float gx = 2.f * (c0 / c2) / (float)(W_ - 1) - 1.f;
            float gy = 2.f * (c1 / c2) / (float)(H_ - 1) - 1.f;
            if (fabsf(gx) <= 1.f && fabsf(gy) <= 1.f && c2 > 0.f) {
                float px = (gx + 1.f) * 0.5f * (float)(W_ - 1);
                float py = (gy + 1.f) * 0.5f * (float)(H_ - 1);
                float x0 = floorf(px), y0 = floorf(py);
                fxI = px - x0; fyI = py - y0;
                int x0i = (int)x0, y0i = (int)y0;
                int pb = ((bi * N_ + lane) * H_ + y0i) * W_ + x0i;
                packwI = pb | ((x0i < W_ - 1) ? (1 << 20) : 0)
                            | ((y0i < H_ - 1) ? (1 << 21) : 0);
            }
        }
        #pragma unroll
        for (int n = 0; n < N_; n++) {
            int pw = __builtin_amdgcn_readlane(packwI, n);   // uniform
            if (pw >= 0) {
                int pb  = pw & 0xFFFFF;
                int dxo = (pw & (1 << 20)) ? 64 : 0;
                int dyo = (pw & (1 << 21)) ? (W_ * 64) : 0;
                const uint32_t* kb = km + ((size_t)(unsigned)pb << 6);
                U[n][0] = kb[lane];
                U[n][1] = kb[lane + dxo];
                U[n][2] = kb[lane + dyo];
                U[n][3] = kb[lane + dyo + dxo];
            }
        }
        vfI = vfeat[(size_t)pI * 64 + lane];
        q1I = q1s[(size_t)pI * 64 + lane];
    };

    auto WEIGHT = [&]() {
        vmC = 0;
        #pragma unroll
        for (int n = 0; n < N_; n++) {
            int pw = __builtin_amdgcn_readlane(packwI, n);   // uniform
            if (pw >= 0) {
                vmC |= (1 << n);
                float wx = readlane_f(fxI, n), wy = readlane_f(fyI, n);
                float w11 = wx * wy;
                float w01 = wx - w11;
                float w10 = wy - w11;
                float w00 = 1.f - wx - wy + w11;
                kf1[n] = w00*bflo(U[n][0]) + w01*bflo(U[n][1]) + w10*bflo(U[n][2]) + w11*bflo(U[n][3]);
                kf2[n] = w00*bfhi(U[n][0]) + w01*bfhi(U[n][1]) + w10*bfhi(U[n][2]) + w11*bfhi(U[n][3]);
            } else { kf1[n] = 0.f; kf2[n] = 0.f; }
        }
        pC = pI; vfC = vfI; q1C = q1I;
    };

    auto FINISH1 = [&]() -> float {
        float l1[N_];
        #pragma unroll
        for (int n = 0; n < N_; n++)
            l1[n] = (vmC & (1 << n)) ? wave_sum64_dpp(q1C * kf1[n]) : NEG_;
        float mx = l1[0];
        #pragma unroll
        for (int n = 1; n < N_; n++) mx = fmaxf(mx, l1[n]);
        float ssum = 0.f, pr[N_];
        #pragma unroll
        for (int n = 0; n < N_; n++) { pr[n] = __expf(l1[n] - mx); ssum += pr[n]; }
        float inv = 1.f / ssum;
        float y1 = 0.f;
        #pragma unroll
        for (int n = 0; n < N_; n++) y1 += pr[n] * kf1[n];
        return vfC + y1 * inv;
    };

    auto FINISH2 = [&](float fcur) {
        f_lds[wid * 64 + lane] = fcur;
        float q2 = bq_lds[lane];
        {
            const float2* wrow = reinterpret_cast<const float2*>(&wq_lds[lane * 66]);
            const float2* fv   = reinterpret_cast<const float2*>(&f_lds[wid * 64]);
            #pragma unroll 8
            for (int cc = 0; cc < 32; cc++) {
                float2 w = wrow[cc]; float2 v = fv[cc];
                q2 += w.x * v.x + w.y * v.y;
            }
        }
        q2 *= 0.125f;

        float l2[N_];
        #pragma unroll
        for (int n = 0; n < N_; n++)
            l2[n] = (vmC & (1 << n)) ? wave_sum64_dpp(q2 * kf2[n]) : NEG_;
        float mx2 = l2[0];
        #pragma unroll
        for (int n = 1; n < N_; n++) mx2 = fmaxf(mx2, l2[n]);
        float ssum2 = 0.f, pr2[N_];
        #pragma unroll
        for (int n = 0; n < N_; n++) { pr2[n] = __expf(l2[n] - mx2); ssum2 += pr2[n]; }
        float inv2 = 1.f / ssum2;
        float y2 = 0.f;
        #pragma unroll
        for (int n = 0; n < N_; n++) y2 += pr2[n] * kf2[n];

        out[(size_t)pC * 64 + lane] = fcur + y2 * inv2;
    };

    int k = widG;
    ISSUE(k);
    while (true) {
        WEIGHT();
        float fcur = FINISH1();          // kf1 dead from here
        int kn = k + nw;
        if (kn < nsel) ISSUE(kn);        // next taps fly under FINISH2
        FINISH2(fcur);
        k = kn;
        if (k >= nsel) break;
    }
}

extern "C" void kernel_launch(void* const* d_in, const int* in_sizes, int n_in,
                              void* d_out, int out_size, void* d_ws, size_t ws_size,
                              hipStream_t stream) {
    const float* img    = (const float*)d_in[0];
    const int*   coords = (const int*)  d_in[1];
    const float* vf     = (const float*)d_in[2];
    const float* proj   = (const float*)d_in[3];
    const float* org    = (const float*)d_in[4];
    const int*   cm     = (const int*)  d_in[5];
    const float* Wq1    = (const float*)d_in[6];
    const float* bq1    = (const float*)d_in[7];
    const float* Wk1    = (const float*)d_in[8];
    const float* bk1    = (const float*)d_in[9];
    const float* Wq2    = (const float*)d_in[10];
    const float* bq2    = (const float*)d_in[11];
    const float* Wk2    = (const float*)d_in[12];
    const float* bk2    = (const float*)d_in[13];

    char* ws = (char*)d_ws;
    uint32_t* km      = (uint32_t*)(ws + OFF_KM);
    float*    q1s     = (float*)   (ws + OFF_Q1S);
    int4*     selcv   = (int4*)    (ws + OFF_SELCV);
    int*      sel_idx = (int*)     (ws + OFF_SELIX);
    int*      nsel    = (int*)     (ws + OFF_NSEL);
    float*    o       = (float*)d_out;

    hipMemsetAsync(nsel, 0, 4, stream);
    keymap_mfma_kernel<<<dim3(NPIX_ / 128), dim3(256), 0, stream>>>(img, Wk1, bk1, Wk2, bk2, km);
    qinit_kernel<<<dim3(P_ / 64), dim3(256), 0, stream>>>(
        vf, Wq1, bq1, cm, (const int4*)coords, q1s, o, sel_idx, selcv, nsel);
    attn_kernel<<<dim3(2048), dim3(256), 0, stream>>>(
        km, vf, proj, org, q1s, Wq2, bq2, sel_idx, selcv, nsel, o);
}

// Round 17
// 139.041 us; speedup vs baseline: 1.2912x; 1.1267x over previous
//
#include <hip/hip_runtime.h>
#include <hip/hip_bf16.h>
#include <stdint.h>

#define B_ 2
#define N_ 9
#define CB_ 80
#define H_ 120
#define W_ 160
#define D_ 64
#define P_ 80000
#define HW_ (H_*W_)        // 19200
#define NPIX_ (B_*N_*HW_)  // 345600
#define NEG_ (-10000.0f)

#define QINIT_BLOCKS  (P_ / 64)        // 1250
#define KEYMAP_BLOCKS (NPIX_ / 128)    // 2700
#define SMEM_BYTES    35072            // max(keymap 26624, qinit 35072)

using short8 = __attribute__((ext_vector_type(8))) short;
using f32x4  = __attribute__((ext_vector_type(4))) float;

static __device__ __forceinline__ float bflo(uint32_t u) {
    return __uint_as_float(u << 16);
}
static __device__ __forceinline__ float bfhi(uint32_t u) {
    return __uint_as_float(u & 0xffff0000u);
}
// HW packed conversion: dword = (bf16(lo), bf16(hi)), RNE — 1 instruction
static __device__ __forceinline__ uint32_t cvt_pk_bf16(float lo, float hi) {
    uint32_t r;
    asm("v_cvt_pk_bf16_f32 %0, %1, %2" : "=v"(r) : "v"(lo), "v"(hi));
    return r;
}

// 64-lane sum entirely on the VALU pipe (DPP), no DS ops.
static __device__ __forceinline__ float wave_sum64_dpp(float x) {
    float f = x;
    f += __int_as_float(__builtin_amdgcn_update_dpp(0, __float_as_int(f), 0x111, 0xF, 0xF, true));
    f += __int_as_float(__builtin_amdgcn_update_dpp(0, __float_as_int(f), 0x112, 0xF, 0xF, true));
    f += __int_as_float(__builtin_amdgcn_update_dpp(0, __float_as_int(f), 0x114, 0xF, 0xF, true));
    f += __int_as_float(__builtin_amdgcn_update_dpp(0, __float_as_int(f), 0x118, 0xF, 0xF, true));
    f += __int_as_float(__builtin_amdgcn_update_dpp(0, __float_as_int(f), 0x142, 0xA, 0xF, true));
    f += __int_as_float(__builtin_amdgcn_update_dpp(0, __float_as_int(f), 0x143, 0xC, 0xF, true));
    return __int_as_float(__builtin_amdgcn_readlane(__float_as_int(f), 63));  // uniform
}
static __device__ __forceinline__ float readlane_f(float v, int l) {
    return __int_as_float(__builtin_amdgcn_readlane(__float_as_int(v), l));
}

// ws layout (bytes)
#define OFF_KM    0
#define OFF_Q1S   ((size_t)NPIX_ * 64 * 4)                 // 88,473,600
#define OFF_SELCV (OFF_Q1S + (size_t)P_ * 64 * 4)          // +20,480,000
#define OFF_SELIX (OFF_SELCV + (size_t)P_ * 16)            // +1,280,000
#define OFF_NSEL  (OFF_SELIX + (size_t)P_ * 4)             // +320,000

// ---------------------------------------------------------------------------
// keymap body (R16 v2 structure, verbatim; smem-pointer plumbing only)
// ---------------------------------------------------------------------------
static __device__ void keymap_body(
    int bid, char* smem,
    const float* __restrict__ img,
    const float* __restrict__ Wk1, const float* __restrict__ bk1,
    const float* __restrict__ Wk2, const float* __restrict__ bk2,
    uint32_t* __restrict__ km)
{
    // row stride 104 bf16 = 208 B = 13*16 B: b128-aligned; rows 0..7 cover all
    // 32 banks exactly once -> b128 read/write at the bank floor
    short (*a_lds)[104] = reinterpret_cast<short (*)[104]>(smem);   // [128][104]
    const int tid  = threadIdx.x;
    const int lane = tid & 63;
    const int wv   = tid >> 6;
    const int lr   = lane & 15;
    const int lg   = lane >> 4;
    const int dw   = (wv >> 1) * 32;     // wave's d half
    const int pxw  = (wv & 1) * 64;      // wave's pixel half

    // ---- W fragments -> registers (once; L2-hot; hidden under A staging) ----
    short8 bf1[3][2], bf2[3][2];
    #pragma unroll
    for (int kc = 0; kc < 3; kc++) {
        const int k = kc * 32 + lg * 8;
        #pragma unroll
        for (int ni = 0; ni < 2; ni++) {
            const int d = dw + ni * 16 + lr;
            short8 v1 = {0,0,0,0,0,0,0,0}, v2 = {0,0,0,0,0,0,0,0};
            if (k < 80) {
                const float4* p1 = reinterpret_cast<const float4*>(Wk1 + d * 80 + k);
                const float4* p2 = reinterpret_cast<const float4*>(Wk2 + d * 80 + k);
                float4 a0 = p1[0], a1 = p1[1];
                float4 c0 = p2[0], c1 = p2[1];
                uint4 u1 = make_uint4(cvt_pk_bf16(a0.x, a0.y), cvt_pk_bf16(a0.z, a0.w),
                                      cvt_pk_bf16(a1.x, a1.y), cvt_pk_bf16(a1.z, a1.w));
                uint4 u2 = make_uint4(cvt_pk_bf16(c0.x, c0.y), cvt_pk_bf16(c0.z, c0.w),
                                      cvt_pk_bf16(c1.x, c1.y), cvt_pk_bf16(c1.z, c1.w));
                v1 = *reinterpret_cast<short8*>(&u1);
                v2 = *reinterpret_cast<short8*>(&u2);
            }
            bf1[kc][ni] = v1; bf2[kc][ni] = v2;
        }
    }

    // ---- A tile -> LDS: thread owns (px, k-octet); b128 writes, cvt_pk ----
    const int pix0 = bid * 128;
    const int bn   = pix0 / HW_;
    const int hw0  = pix0 - bn * HW_;
    const float* ibase = img + (size_t)bn * CB_ * HW_ + hw0;
    {
        const int px = tid & 127;
        const int kh = (tid >> 7) * 48;          // 0 or 48
        #pragma unroll
        for (int oct = 0; oct < 6; oct++) {
            const int k = kh + oct * 8;
            uint32_t w0 = 0, w1 = 0, w2 = 0, w3 = 0;
            if (k < 80) {
                float e0 = ibase[(k + 0) * HW_ + px], e1 = ibase[(k + 1) * HW_ + px];
                float e2 = ibase[(k + 2) * HW_ + px], e3 = ibase[(k + 3) * HW_ + px];
                float e4 = ibase[(k + 4) * HW_ + px], e5 = ibase[(k + 5) * HW_ + px];
                float e6 = ibase[(k + 6) * HW_ + px], e7 = ibase[(k + 7) * HW_ + px];
                w0 = cvt_pk_bf16(e0, e1); w1 = cvt_pk_bf16(e2, e3);
                w2 = cvt_pk_bf16(e4, e5); w3 = cvt_pk_bf16(e6, e7);
            }
            uint4 v = make_uint4(w0, w1, w2, w3);
            *reinterpret_cast<uint4*>(&a_lds[px][k]) = v;
        }
    }
    __syncthreads();

    f32x4 acc1[4][2], acc2[4][2];
    #pragma unroll
    for (int mi = 0; mi < 4; mi++)
        #pragma unroll
        for (int ni = 0; ni < 2; ni++) {
            acc1[mi][ni] = (f32x4){0.f, 0.f, 0.f, 0.f};
            acc2[mi][ni] = (f32x4){0.f, 0.f, 0.f, 0.f};
        }

    #pragma unroll
    for (int kc = 0; kc < 3; kc++) {
        const int k0 = kc * 32;
        short8 av[4];
        #pragma unroll
        for (int mi = 0; mi < 4; mi++)
            av[mi] = *reinterpret_cast<const short8*>(&a_lds[pxw + mi * 16 + lr][k0 + lg * 8]);
        #pragma unroll
        for (int mi = 0; mi < 4; mi++) {
            #pragma unroll
            for (int ni = 0; ni < 2; ni++) {
                acc1[mi][ni] = __builtin_amdgcn_mfma_f32_16x16x32_bf16(av[mi], bf1[kc][ni], acc1[mi][ni], 0, 0, 0);
                acc2[mi][ni] = __builtin_amdgcn_mfma_f32_16x16x32_bf16(av[mi], bf2[kc][ni], acc2[mi][ni], 0, 0, 0);
            }
        }
    }

    // epilogue: add bias, pack (set1,set2) -> one dword, coalesced stores
    #pragma unroll
    for (int ni = 0; ni < 2; ni++) {
        const int d = dw + ni * 16 + lr;
        const float b1 = bk1[d], b2 = bk2[d];
        #pragma unroll
        for (int mi = 0; mi < 4; mi++) {
            #pragma unroll
            for (int r = 0; r < 4; r++) {
                int pix = pix0 + pxw + mi * 16 + lg * 4 + r;
                km[(size_t)pix * 64 + d] = cvt_pk_bf16(acc1[mi][ni][r] + b1, acc2[mi][ni][r] + b2);
            }
        }
    }
}

// ---------------------------------------------------------------------------
// qinit body (R16 verbatim; smem-pointer plumbing only)
// ---------------------------------------------------------------------------
static __device__ void qinit_body(
    int bid, char* smem,
    const float* __restrict__ vfeat,
    const float* __restrict__ Wq1, const float* __restrict__ bq1,
    const int*   __restrict__ cmask,
    const int4*  __restrict__ coords4,
    float* __restrict__ q1s, float* __restrict__ out,
    int* __restrict__ sel_idx, int4* __restrict__ selcv, int* __restrict__ nsel)
{
    float (*wt_lds)[68] = reinterpret_cast<float (*)[68]>(smem);            // [64][68]
    float (*vf_lds)[68] = reinterpret_cast<float (*)[68]>(smem + 17408);    // [64][68]
    float* bq_lds       = reinterpret_cast<float*>(smem + 34816);           // [64]
    const int tid = threadIdx.x;
    const int pt0 = bid * 64;

    if (tid < 64) {
        int p2 = pt0 + tid;
        bool s = cmask[p2] > 1;
        unsigned long long m = __ballot(s);
        int base = 0;
        if (tid == 0 && m) base = atomicAdd(nsel, __popcll(m));
        base = __shfl(base, 0);
        if (s) {
            int off = __popcll(m & ((1ull << tid) - 1ull));
            sel_idx[base + off] = p2;
            selcv[base + off]   = coords4[p2];
        }
    }

    for (int idx = tid; idx < 4096; idx += 256) {
        int d = idx >> 6, c = idx & 63;
        wt_lds[c][d] = Wq1[idx];
    }
    if (tid < 64) bq_lds[tid] = bq1[tid];

    const float4* vf4 = reinterpret_cast<const float4*>(vfeat + (size_t)pt0 * 64);
    float4* out4 = reinterpret_cast<float4*>(out + (size_t)pt0 * 64);
    for (int idx = tid; idx < 1024; idx += 256) {
        float4 v = vf4[idx];
        out4[idx] = v;
        int r = idx >> 4, c4 = (idx & 15) * 4;
        *reinterpret_cast<float4*>(&vf_lds[r][c4]) = v;
    }
    __syncthreads();

    const int pl = tid >> 2;
    const int d0 = (tid & 3) * 16;
    float acc[16];
    #pragma unroll
    for (int i = 0; i < 16; i++) acc[i] = bq_lds[d0 + i];
    for (int k = 0; k < 64; k++) {
        float a = vf_lds[pl][k];
        const float4* wr = reinterpret_cast<const float4*>(&wt_lds[k][d0]);
        float4 w0 = wr[0], w1 = wr[1], w2 = wr[2], w3 = wr[3];
        acc[0]  += a * w0.x; acc[1]  += a * w0.y; acc[2]  += a * w0.z; acc[3]  += a * w0.w;
        acc[4]  += a * w1.x; acc[5]  += a * w1.y; acc[6]  += a * w1.z; acc[7]  += a * w1.w;
        acc[8]  += a * w2.x; acc[9]  += a * w2.y; acc[10] += a * w2.z; acc[11] += a * w2.w;
        acc[12] += a * w3.x; acc[13] += a * w3.y; acc[14] += a * w3.z; acc[15] += a * w3.w;
    }
    float4* q4 = reinterpret_cast<float4*>(q1s + (size_t)(pt0 + pl) * 64 + d0);
    #pragma unroll
    for (int j = 0; j < 4; j++) {
        q4[j] = make_float4(acc[4*j] * 0.125f, acc[4*j+1] * 0.125f,
                            acc[4*j+2] * 0.125f, acc[4*j+3] * 0.125f);
    }
}

// ---------------------------------------------------------------------------
// Kernel 1 (fused): blocks 0..1249 -> qinit, 1250..3949 -> keymap.
// Both independent & latency-bound: co-residency hides qinit's 12 us.
// ---------------------------------------------------------------------------
__global__ __launch_bounds__(256) void fused1_kernel(
    const float* __restrict__ img,
    const float* __restrict__ Wk1, const float* __restrict__ bk1,
    const float* __restrict__ Wk2, const float* __restrict__ bk2,
    uint32_t* __restrict__ km,
    const float* __restrict__ vfeat,
    const float* __restrict__ Wq1, const float* __restrict__ bq1,
    const int*   __restrict__ cmask,
    const int4*  __restrict__ coords4,
    float* __restrict__ q1s, float* __restrict__ out,
    int* __restrict__ sel_idx, int4* __restrict__ selcv, int* __restrict__ nsel)
{
    __shared__ __align__(16) char smem[SMEM_BYTES];
    const int bid = blockIdx.x;
    if (bid < QINIT_BLOCKS) {
        qinit_body(bid, smem, vfeat, Wq1, bq1, cmask, coords4,
                   q1s, out, sel_idx, selcv, nsel);
    } else {
        keymap_body(bid - QINIT_BLOCKS, smem, img, Wk1, bk1, Wk2, bk2, km);
    }
}

// ---------------------------------------------------------------------------
// Kernel 2: dense sel-only attention (DPP reductions, readlane broadcasts,
// WEIGHT -> FINISH1 -> ISSUE(next) -> FINISH2 pipeline).  (unchanged, R13)
// ---------------------------------------------------------------------------
__global__ __launch_bounds__(256) void attn_kernel(
    const uint32_t* __restrict__ km,
    const float* __restrict__ vfeat,
    const float* __restrict__ proj,
    const float* __restrict__ origins,
    const float* __restrict__ q1s,
    const float* __restrict__ Wq2, const float* __restrict__ bq2,
    const int*  __restrict__ sel_idx,
    const int4* __restrict__ selcv4,
    const int*  __restrict__ nsel_ptr,
    float* __restrict__ out)
{
    __shared__ __align__(16) float wq_lds[64 * 66];
    __shared__ __align__(16) float f_lds[4 * 64];
    __shared__ float bq_lds[64];
    __shared__ float proj_lds[B_ * N_ * 12];   // 216
    const int tid = threadIdx.x;

    for (int idx = tid; idx < 4096; idx += 256) {
        int d = idx >> 6, c = idx & 63;
        wq_lds[d * 66 + c] = Wq2[idx];
    }
    if (tid < 64) bq_lds[tid] = bq2[tid];
    if (tid < B_ * N_ * 12) proj_lds[tid] = proj[tid];
    __syncthreads();

    const int lane = tid & 63;
    const int wid  = tid >> 6;
    const int nw   = gridDim.x * 4;
    const int widG = blockIdx.x * 4 + wid;
    const int nsel = *nsel_ptr;

    if (widG >= nsel) return;

    const float o0x = origins[0], o0y = origins[1], o0z = origins[2];
    const float o1x = origins[3], o1y = origins[4], o1z = origins[5];

    uint32_t U[N_][4];
    float    kf1[N_], kf2[N_];
    int      packwI;  float fxI, fyI;
    int      pI;      float vfI, q1I;
    int      pC, vmC; float vfC, q1C;

    auto ISSUE = [&](int kk) {
        pI = sel_idx[kk];
        const int4 cv = selcv4[kk];
        const int  bi   = cv.w;
        const float wldx = (float)cv.x * 0.16f + (bi ? o1x : o0x);
        const float wldy = (float)cv.y * 0.16f + (bi ? o1y : o0y);
        const float wldz = (float)cv.z * 0.16f + (bi ? o1z : o0z);
        packwI = -1; fxI = 0.f; fyI = 0.f;
        if (lane < N_) {
            const float* Pr = &proj_lds[(bi * N_ + lane) * 12];
            float c0 = Pr[0]*wldx + Pr[1]*wldy + Pr[2]*wldz  + Pr[3];
            float c1 = Pr[4]*wldx + Pr[5]*wldy + Pr[6]*wldz  + Pr[7];
            float c2 = Pr[8]*wldx + Pr[9]*wldy + Pr[10]*wldz + Pr[11];
            float gx = 2.f * (c0 / c2) / (float)(W_ - 1) - 1.f;
            float gy = 2.f * (c1 / c2) / (float)(H_ - 1) - 1.f;
            if (fabsf(gx) <= 1.f && fabsf(gy) <= 1.f && c2 > 0.f) {
                float px = (gx + 1.f) * 0.5f * (float)(W_ - 1);
                float py = (gy + 1.f) * 0.5f * (float)(H_ - 1);
                float x0 = floorf(px), y0 = floorf(py);
                fxI = px - x0; fyI = py - y0;
                int x0i = (int)x0, y0i = (int)y0;
                int pb = ((bi * N_ + lane) * H_ + y0i) * W_ + x0i;
                packwI = pb | ((x0i < W_ - 1) ? (1 << 20) : 0)
                            | ((y0i < H_ - 1) ? (1 << 21) : 0);
            }
        }
        #pragma unroll
        for (int n = 0; n < N_; n++) {
            int pw = __builtin_amdgcn_readlane(packwI, n);   // uniform
            if (pw >= 0) {
                int pb  = pw & 0xFFFFF;
                int dxo = (pw & (1 << 20)) ? 64 : 0;
                int dyo = (pw & (1 << 21)) ? (W_ * 64) : 0;
                const uint32_t* kb = km + ((size_t)(unsigned)pb << 6);
                U[n][0] = kb[lane];
                U[n][1] = kb[lane + dxo];
                U[n][2] = kb[lane + dyo];
                U[n][3] = kb[lane + dyo + dxo];
            }
        }
        vfI = vfeat[(size_t)pI * 64 + lane];
        q1I = q1s[(size_t)pI * 64 + lane];
    };

    auto WEIGHT = [&]() {
        vmC = 0;
        #pragma unroll
        for (int n = 0; n < N_; n++) {
            int pw = __builtin_amdgcn_readlane(packwI, n);   // uniform
            if (pw >= 0) {
                vmC |= (1 << n);
                float wx = readlane_f(fxI, n), wy = readlane_f(fyI, n);
                float w11 = wx * wy;
                float w01 = wx - w11;
                float w10 = wy - w11;
                float w00 = 1.f - wx - wy + w11;
                kf1[n] = w00*bflo(U[n][0]) + w01*bflo(U[n][1]) + w10*bflo(U[n][2]) + w11*bflo(U[n][3]);
                kf2[n] = w00*bfhi(U[n][0]) + w01*bfhi(U[n][1]) + w10*bfhi(U[n][2]) + w11*bfhi(U[n][3]);
            } else { kf1[n] = 0.f; kf2[n] = 0.f; }
        }
        pC = pI; vfC = vfI; q1C = q1I;
    };

    auto FINISH1 = [&]() -> float {
        float l1[N_];
        #pragma unroll
        for (int n = 0; n < N_; n++)
            l1[n] = (vmC & (1 << n)) ? wave_sum64_dpp(q1C * kf1[n]) : NEG_;
        float mx = l1[0];
        #pragma unroll
        for (int n = 1; n < N_; n++) mx = fmaxf(mx, l1[n]);
        float ssum = 0.f, pr[N_];
        #pragma unroll
        for (int n = 0; n < N_; n++) { pr[n] = __expf(l1[n] - mx); ssum += pr[n]; }
        float inv = 1.f / ssum;
        float y1 = 0.f;
        #pragma unroll
        for (int n = 0; n < N_; n++) y1 += pr[n] * kf1[n];
        return vfC + y1 * inv;
    };

    auto FINISH2 = [&](float fcur) {
        f_lds[wid * 64 + lane] = fcur;
        float q2 = bq_lds[lane];
        {
            const float2* wrow = reinterpret_cast<const float2*>(&wq_lds[lane * 66]);
            const float2* fv   = reinterpret_cast<const float2*>(&f_lds[wid * 64]);
            #pragma unroll 8
            for (int cc = 0; cc < 32; cc++) {
                float2 w = wrow[cc]; float2 v = fv[cc];
                q2 += w.x * v.x + w.y * v.y;
            }
        }
        q2 *= 0.125f;

        float l2[N_];
        #pragma unroll
        for (int n = 0; n < N_; n++)
            l2[n] = (vmC & (1 << n)) ? wave_sum64_dpp(q2 * kf2[n]) : NEG_;
        float mx2 = l2[0];
        #pragma unroll
        for (int n = 1; n < N_; n++) mx2 = fmaxf(mx2, l2[n]);
        float ssum2 = 0.f, pr2[N_];
        #pragma unroll
        for (int n = 0; n < N_; n++) { pr2[n] = __expf(l2[n] - mx2); ssum2 += pr2[n]; }
        float inv2 = 1.f / ssum2;
        float y2 = 0.f;
        #pragma unroll
        for (int n = 0; n < N_; n++) y2 += pr2[n] * kf2[n];

        out[(size_t)pC * 64 + lane] = fcur + y2 * inv2;
    };

    int k = widG;
    ISSUE(k);
    while (true) {
        WEIGHT();
        float fcur = FINISH1();          // kf1 dead from here
        int kn = k + nw;
        if (kn < nsel) ISSUE(kn);        // next taps fly under FINISH2
        FINISH2(fcur);
        k = kn;
        if (k >= nsel) break;
    }
}

extern "C" void kernel_launch(void* const* d_in, const int* in_sizes, int n_in,
                              void* d_out, int out_size, void* d_ws, size_t ws_size,
                              hipStream_t stream) {
    const float* img    = (const float*)d_in[0];
    const int*   coords = (const int*)  d_in[1];
    const float* vf     = (const float*)d_in[2];
    const float* proj   = (const float*)d_in[3];
    const float* org    = (const float*)d_in[4];
    const int*   cm     = (const int*)  d_in[5];
    const float* Wq1    = (const float*)d_in[6];
    const float* bq1    = (const float*)d_in[7];
    const float* Wk1    = (const float*)d_in[8];
    const float* bk1    = (const float*)d_in[9];
    const float* Wq2    = (const float*)d_in[10];
    const float* bq2    = (const float*)d_in[11];
    const float* Wk2    = (const float*)d_in[12];
    const float* bk2    = (const float*)d_in[13];

    char* ws = (char*)d_ws;
    uint32_t* km      = (uint32_t*)(ws + OFF_KM);
    float*    q1s     = (float*)   (ws + OFF_Q1S);
    int4*     selcv   = (int4*)    (ws + OFF_SELCV);
    int*      sel_idx = (int*)     (ws + OFF_SELIX);
    int*      nsel    = (int*)     (ws + OFF_NSEL);
    float*    o       = (float*)d_out;

    hipMemsetAsync(nsel, 0, 4, stream);
    fused1_kernel<<<dim3(QINIT_BLOCKS + KEYMAP_BLOCKS), dim3(256), 0, stream>>>(
        img, Wk1, bk1, Wk2, bk2, km,
        vf, Wq1, bq1, cm, (const int4*)coords, q1s, o, sel_idx, selcv, nsel);
    attn_kernel<<<dim3(2048), dim3(256), 0, stream>>>(
        km, vf, proj, org, q1s, Wq2, bq2, sel_idx, selcv, nsel, o);
}